// Round 14
// baseline (128.554 us; speedup 1.0000x reference)
//
#include <hip/hip_runtime.h>
#include <hip/hip_bf16.h>
#include <cstdint>

// STFT magnitude via real-packed radix-4 FFT (round 14 = r13 with stage-4 twiddle FIX).
// r13 failed (absmax 97) because the hoisted stage-4 twiddles used stage-6's
// stride: tst[4*j0,8*j0,12*j0]. Template fft_stage<4> has STRIDE=16 ->
// correct twiddles are tst[16*j0], tst[32*j0], tst[48*j0]  (W64^j = W1024^{16j}).
// All other index math re-verified against the template (see r13 notes):
//   - stages 0+2 in registers == natural-order DFT16 of lane's samples
//     x[lane+64u] (r10-verified fft16); scatter to block {16G+k}, G=base-4
//     reverse of lane, SW fold = k^(G&15).
//   - stages 4+6 in registers on closed set {j0+16a+64b2+256B}; stage-4 j=j0,
//     stage-6 j=j0+16*mp with twiddles tst[4j],tst[8j],tst[12j] (STRIDE=4). OK.
//   - stage 8 + mirror-pair unpack + one-barrier 16-frame write: r12-identical.
// Lessons kept: never trade occupancy (r5/r11); no per-phase barriers (r11).

#define FILT   2048
#define HOP    512
#define CUT    1025
#define NBATCH 32
#define TFR    626
#define NFR    (NBATCH * TFR)      // 20032
#define LSIG   320000
#define LPAD   (LSIG + FILT)       // 322048
#define N2     1024                // complex FFT length

typedef __attribute__((ext_vector_type(8))) short short8;

__device__ __forceinline__ short bf16r(float f) {
  __hip_bfloat16 h = __float2bfloat16(f);
  return __builtin_bit_cast(short, h);
}
__device__ __forceinline__ float bf2f(uint32_t u) {
  return __builtin_bit_cast(float, u << 16);
}

__device__ __forceinline__ short8 pack8(float4 a, float4 b) {
  short8 v;
  v[0] = bf16r(a.x); v[1] = bf16r(a.y); v[2] = bf16r(a.z); v[3] = bf16r(a.w);
  v[4] = bf16r(b.x); v[5] = bf16r(b.y); v[6] = bf16r(b.z); v[7] = bf16r(b.w);
  return v;
}

// -------- stage 1a: reflect-padded signal, f32 -> bf16 [32][LPAD] --------
__global__ void pad_signal(const float* __restrict__ x, short* __restrict__ XP) {
  const int b = blockIdx.y;
  const int i0 = (blockIdx.x * 256 + threadIdx.x) * 8;
  if (i0 >= LPAD) return;
  const float* xb = x + (size_t)b * LSIG;
  const int j0 = i0 - 1024;
  short8 v;
  if (j0 >= 0 && j0 + 8 <= LSIG) {
    float4 a = *(const float4*)(xb + j0);
    float4 c = *(const float4*)(xb + j0 + 4);
    v = pack8(a, c);
  } else {
    #pragma unroll
    for (int e = 0; e < 8; ++e) {
      int j = j0 + e;
      j = j < 0 ? -j : (j >= LSIG ? 2 * LSIG - 2 - j : j);
      v[e] = bf16r(xb[j]);
    }
  }
  *(short8*)&XP[(size_t)b * LPAD + i0] = v;
}

// -------- stage 1b: twiddle + hann tables --------
__global__ void make_tables(float* __restrict__ hann, float2* __restrict__ Tst,
                            float2* __restrict__ Tun) {
  const int i = blockIdx.x * 256 + threadIdx.x;    // 0..2047
  const float PI2 = 6.283185307179586f;
  if (i < 2048) hann[i] = 0.5f - 0.5f * cosf(PI2 * (float)i / 2048.0f);
  if (i < 1024) {
    float s, c;
    sincosf(-PI2 * (float)i / 1024.0f, &s, &c);
    Tst[i] = make_float2(c, s);                    // W_1024^i (forward)
    sincosf(-PI2 * (float)i / 2048.0f, &s, &c);
    Tun[i] = make_float2(c, s);                    // W_2048^i (unpack)
  }
}

__device__ __forceinline__ float2 cmul(float2 a, float2 b) {
  return make_float2(a.x * b.x - a.y * b.y, a.x * b.y + a.y * b.x);
}
__device__ __forceinline__ float2 cmulc(float2 a, float cx, float cy) {
  return make_float2(a.x * cx - a.y * cy, a.x * cy + a.y * cx);
}

__device__ __forceinline__ int SW(int i) { return i ^ ((i >> 4) & 15); }

// natural-order 16-pt DFT in registers (r10-verified): Y[k] = sum_j y[j] W16^{jk}
__device__ __forceinline__ void fft16(float2* y) {
  static constexpr float TX[4][4] = {
    {1.f, 1.f, 1.f, 1.f},
    {1.f,  0.92387953251128674f,  0.70710678118654752f,  0.38268343236508978f},
    {1.f,  0.70710678118654752f,  0.f,                  -0.70710678118654752f},
    {1.f,  0.38268343236508978f, -0.70710678118654752f, -0.92387953251128674f}};
  static constexpr float TY[4][4] = {
    {0.f, 0.f, 0.f, 0.f},
    {0.f, -0.38268343236508978f, -0.70710678118654752f, -0.92387953251128674f},
    {0.f, -0.70710678118654752f, -1.f,                  -0.70710678118654752f},
    {0.f, -0.92387953251128674f, -0.70710678118654752f,  0.38268343236508978f}};
  float2 G[16];
  #pragma unroll
  for (int n0 = 0; n0 < 4; ++n0) {
    float2 a0 = y[n0], a1 = y[n0 + 4], a2 = y[n0 + 8], a3 = y[n0 + 12];
    float2 e = make_float2(a0.x + a2.x, a0.y + a2.y);
    float2 f = make_float2(a0.x - a2.x, a0.y - a2.y);
    float2 g = make_float2(a1.x + a3.x, a1.y + a3.y);
    float2 h = make_float2(a1.x - a3.x, a1.y - a3.y);
    float2 F0 = make_float2(e.x + g.x, e.y + g.y);
    float2 F1 = make_float2(f.x + h.y, f.y - h.x);   // f - i*h
    float2 F2 = make_float2(e.x - g.x, e.y - g.y);
    float2 F3 = make_float2(f.x - h.y, f.y + h.x);   // f + i*h
    G[n0 * 4 + 0] = F0;
    G[n0 * 4 + 1] = cmulc(F1, TX[n0][1], TY[n0][1]);
    G[n0 * 4 + 2] = cmulc(F2, TX[n0][2], TY[n0][2]);
    G[n0 * 4 + 3] = cmulc(F3, TX[n0][3], TY[n0][3]);
  }
  #pragma unroll
  for (int q = 0; q < 4; ++q) {
    float2 a0 = G[q], a1 = G[4 + q], a2 = G[8 + q], a3 = G[12 + q];
    float2 e = make_float2(a0.x + a2.x, a0.y + a2.y);
    float2 f = make_float2(a0.x - a2.x, a0.y - a2.y);
    float2 g = make_float2(a1.x + a3.x, a1.y + a3.y);
    float2 h = make_float2(a1.x - a3.x, a1.y - a3.y);
    y[q]      = make_float2(e.x + g.x, e.y + g.y);
    y[q + 4]  = make_float2(f.x + h.y, f.y - h.x);
    y[q + 8]  = make_float2(e.x - g.x, e.y - g.y);
    y[q + 12] = make_float2(f.x - h.y, f.y + h.x);
  }
}

// radix-4 DIT stage via LDS (used for LOG=8 only)
template<int LOG>
__device__ __forceinline__ void fft_stage(float2* z, const float2* tw, int lane) {
  constexpr int M4 = 1 << LOG;
  constexpr int STRIDE = 1 << (8 - LOG);
  #pragma unroll
  for (int u = 0; u < 4; ++u) {
    const int bf = u * 64 + lane;
    const int j  = bf & (M4 - 1);
    const int i0 = ((bf >> LOG) << (LOG + 2)) | j;
    const int i1 = i0 + M4, i2 = i0 + 2 * M4, i3 = i0 + 3 * M4;
    const int p0 = SW(i0), p1 = SW(i1), p2 = SW(i2), p3 = SW(i3);
    float2 a = z[p0], b = z[p1], c = z[p2], d = z[p3];
    if (LOG > 0) {
      b = cmul(b, tw[j * STRIDE]);
      c = cmul(c, tw[2 * j * STRIDE]);
      d = cmul(d, tw[3 * j * STRIDE]);
    }
    const float2 t0 = make_float2(a.x + c.x, a.y + c.y);
    const float2 t1 = make_float2(a.x - c.x, a.y - c.y);
    const float2 t2 = make_float2(b.x + d.x, b.y + d.y);
    const float2 t3 = make_float2(b.x - d.x, b.y - d.y);
    z[p0] = make_float2(t0.x + t2.x, t0.y + t2.y);
    z[p1] = make_float2(t1.x + t3.y, t1.y - t3.x);   // t1 - i*t3
    z[p2] = make_float2(t0.x - t2.x, t0.y - t2.y);
    z[p3] = make_float2(t1.x - t3.y, t1.y + t3.x);   // t1 + i*t3
  }
}

// -------- stage 2: windowed rFFT magnitude, 1 wave = 1 frame --------
__global__ __launch_bounds__(256)
void stft_fft(const short* __restrict__ XP, const float* __restrict__ hann,
              const float2* __restrict__ Tst, const float2* __restrict__ Tun,
              float* __restrict__ out)
{
  __shared__ float2 zsh[4][1024];    // per-wave z, XOR-swizzled   32768 B
  __shared__ float2 tst[1024];       // stage twiddles              8192 B
  __shared__ ushort mag[16][1032];   // bf16 mags, 16 frames       33024 B  (73984 total)

  const int tid = threadIdx.x, wv = tid >> 6, lane = tid & 63;
  #pragma unroll
  for (int u = 0; u < 4; ++u) tst[u * 256 + tid] = Tst[u * 256 + tid];
  __syncthreads();                   // tables ready

  float2* z = zsh[wv];
  const int bid = blockIdx.x;

  // per-lane geometry
  const int G  = ((lane & 3) << 4) | (lane & 12) | (lane >> 4);  // base-4 reverse
  const int zb = 16 * G, gm = G & 15;
  const int j0 = lane & 15, B = lane >> 4;

  // hoisted stage-4/6 twiddles (frame-independent).
  // Stage 4: STRIDE=16 -> W1024^{16*j0 * {1,2,3}}   [THE r13 BUG: was 4*j0]
  const float2 w41 = tst[16 * j0], w42 = tst[32 * j0], w43 = tst[48 * j0];
  // Stage 6: STRIDE=4, j = j0+16*mp -> W1024^{4j * {1,2,3}}
  float2 w6[4][3];
  #pragma unroll
  for (int mp = 0; mp < 4; ++mp) {
    const int jj = 4 * (j0 + 16 * mp);
    w6[mp][0] = tst[jj]; w6[mp][1] = tst[2 * jj]; w6[mp][2] = tst[3 * jj];
  }

  for (int q = 0; q < 4; ++q) {
    const int f = bid * 16 + q * 4 + wv;
    const int b = f / TFR, t = f - b * TFR;
    const short* base = XP + (size_t)b * LPAD + (size_t)t * HOP;

    // load pairs (coalesced), window, stages 0+2 in registers (= DFT16 of
    // the lane's decimated samples), scatter results to block {16G + k}
    float2 y[16];
    #pragma unroll
    for (int u = 0; u < 16; ++u) {
      const int n = u * 64 + lane;
      const uint32_t pr = *(const uint32_t*)(base + 2 * n);
      const float2 h = *(const float2*)(hann + 2 * n);
      y[u] = make_float2(bf2f(pr & 0xffffu) * h.x, bf2f(pr >> 16) * h.y);
    }
    fft16(y);
    #pragma unroll
    for (int k = 0; k < 16; ++k) z[zb + (k ^ gm)] = y[k];

    // stages 4+6 in registers on set {j0 + 16a + 64b2 + 256B}
    float2 g[4][4];
    #pragma unroll
    for (int a = 0; a < 4; ++a)
      #pragma unroll
      for (int b2 = 0; b2 < 4; ++b2)
        g[a][b2] = z[16 * (a + 4 * b2 + 16 * B) + (j0 ^ (a + 4 * b2))];
    #pragma unroll
    for (int b2 = 0; b2 < 4; ++b2) {                  // stage 4 (over a), j=j0
      float2 a0 = g[0][b2];
      float2 a1 = cmul(g[1][b2], w41);
      float2 a2 = cmul(g[2][b2], w42);
      float2 a3 = cmul(g[3][b2], w43);
      const float2 t0 = make_float2(a0.x + a2.x, a0.y + a2.y);
      const float2 t1 = make_float2(a0.x - a2.x, a0.y - a2.y);
      const float2 t2 = make_float2(a1.x + a3.x, a1.y + a3.y);
      const float2 t3 = make_float2(a1.x - a3.x, a1.y - a3.y);
      g[0][b2] = make_float2(t0.x + t2.x, t0.y + t2.y);
      g[1][b2] = make_float2(t1.x + t3.y, t1.y - t3.x);
      g[2][b2] = make_float2(t0.x - t2.x, t0.y - t2.y);
      g[3][b2] = make_float2(t1.x - t3.y, t1.y + t3.x);
    }
    #pragma unroll
    for (int mp = 0; mp < 4; ++mp) {                  // stage 6 (over b2), j=j0+16mp
      float2 a0 = g[mp][0];
      float2 a1 = cmul(g[mp][1], w6[mp][0]);
      float2 a2 = cmul(g[mp][2], w6[mp][1]);
      float2 a3 = cmul(g[mp][3], w6[mp][2]);
      const float2 t0 = make_float2(a0.x + a2.x, a0.y + a2.y);
      const float2 t1 = make_float2(a0.x - a2.x, a0.y - a2.y);
      const float2 t2 = make_float2(a1.x + a3.x, a1.y + a3.y);
      const float2 t3 = make_float2(a1.x - a3.x, a1.y - a3.y);
      g[mp][0] = make_float2(t0.x + t2.x, t0.y + t2.y);
      g[mp][1] = make_float2(t1.x + t3.y, t1.y - t3.x);
      g[mp][2] = make_float2(t0.x - t2.x, t0.y - t2.y);
      g[mp][3] = make_float2(t1.x - t3.y, t1.y + t3.x);
    }
    #pragma unroll
    for (int mp = 0; mp < 4; ++mp)
      #pragma unroll
      for (int m2 = 0; m2 < 4; ++m2)
        z[16 * (mp + 4 * m2 + 16 * B) + (j0 ^ (mp + 4 * m2))] = g[mp][m2];

    fft_stage<8>(z, tst, lane);

    // mirror-pair unpack: bins k and 1024-k from one (Zk,Zm,w) triple
    ushort* mrow = mag[q * 4 + wv];
    #pragma unroll
    for (int v = 0; v < 8; ++v) {
      const int k = v * 64 + lane;                     // 0..511
      const float2 Zk = z[SW(k)];
      const int km = (N2 - k) & (N2 - 1);
      const float2 Zm = z[SW(km)];
      const float xer = 0.5f * (Zk.x + Zm.x);
      const float xei = 0.5f * (Zk.y - Zm.y);
      const float xor_ = 0.5f * (Zk.y + Zm.y);
      const float xoi = -0.5f * (Zk.x - Zm.x);
      const float2 w = Tun[k];                         // global, coalesced, L1-hot
      const float px = w.x * xor_ - w.y * xoi;
      const float py = w.x * xoi + w.y * xor_;
      const float Xr = xer + px, Xi = xei + py;
      const float Yr = xer - px, Yi = xei - py;
      mrow[k]        = (ushort)bf16r(sqrtf(Xr * Xr + Xi * Xi));
      mrow[1024 - k] = (ushort)bf16r(sqrtf(Yr * Yr + Yi * Yi));
    }
    if (lane == 0) {
      const float2 Zc = z[SW(512)];
      mrow[512] = (ushort)bf16r(sqrtf(Zc.x * Zc.x + Zc.y * Zc.y));
    }
  }
  __syncthreads();                   // the ONLY post-prologue barrier

  // single write phase: 16 consecutive frames per bin -> fully-dirty 64B lines
  const int fq0 = bid * 16;
  const int b0 = fq0 / TFR, t0 = fq0 - b0 * TFR;
  if (t0 + 15 < TFR) {
    for (int kk = tid; kk < 1025; kk += 256) {
      float* p = out + (size_t)b0 * (CUT * TFR) + (size_t)kk * TFR + t0;
      #pragma unroll
      for (int w2 = 0; w2 < 8; ++w2)
        *(float2*)(p + 2 * w2) =
            make_float2(bf2f(mag[2 * w2][kk]), bf2f(mag[2 * w2 + 1][kk]));
    }
  } else {
    for (int kk = tid; kk < 1025; kk += 256) {
      #pragma unroll
      for (int w2 = 0; w2 < 16; ++w2) {
        const int ff = fq0 + w2;
        const int bb = ff / TFR, tt = ff - bb * TFR;
        out[(size_t)bb * (CUT * TFR) + (size_t)kk * TFR + tt] = bf2f(mag[w2][kk]);
      }
    }
  }
}

// -------- fallback: reg-staged 128x128 MFMA GEMM (no ws needed) --------
typedef __attribute__((ext_vector_type(4))) float f32x4;

__global__ __launch_bounds__(256, 2)
void stft_gemm_fb(const float* __restrict__ basis, const float* __restrict__ x,
                  float* __restrict__ out)
{
  __shared__ alignas(16) short sA[2][128][64];
  __shared__ alignas(16) short sB[128][64];

  const int tid  = threadIdx.x;
  const int wave = tid >> 6;
  const int lane = tid & 63;
  const int n0 = blockIdx.x * 128;
  const int m0 = blockIdx.y * 128;

  f32x4 acc_r[4][4], acc_i[4][4];
  #pragma unroll
  for (int i = 0; i < 4; ++i)
    #pragma unroll
    for (int j = 0; j < 4; ++j) { acc_r[i][j] = (f32x4)0.f; acc_i[i][j] = (f32x4)0.f; }

  const int sr = tid >> 1;
  const int sh = (tid & 1) * 32;

  for (int k0 = 0; k0 < FILT; k0 += 64) {
    #pragma unroll
    for (int p = 0; p < 2; ++p) {
      const int k = m0 + sr;
      short8 v[4];
      if (k < CUT) {
        const float* src = basis + (size_t)(p * CUT + k) * FILT + k0 + sh;
        #pragma unroll
        for (int qq = 0; qq < 4; ++qq) {
          float4 a = *(const float4*)(src + qq * 8);
          float4 b = *(const float4*)(src + qq * 8 + 4);
          v[qq] = pack8(a, b);
        }
      } else {
        #pragma unroll
        for (int qq = 0; qq < 4; ++qq) v[qq] = (short8)(short)0;
      }
      #pragma unroll
      for (int qq = 0; qq < 4; ++qq) *(short8*)&sA[p][sr][sh + qq * 8] = v[qq];
    }
    {
      const int f = n0 + sr;
      short8 v[4];
      if (f < NFR) {
        const int b = f / TFR, t = f - b * TFR;
        const float* xb = x + (size_t)b * LSIG;
        const int j0 = t * HOP + k0 + sh - 1024;
        if (j0 >= 0 && j0 + 32 <= LSIG) {
          #pragma unroll
          for (int qq = 0; qq < 4; ++qq) {
            float4 a  = *(const float4*)(xb + j0 + qq * 8);
            float4 b2 = *(const float4*)(xb + j0 + qq * 8 + 4);
            v[qq] = pack8(a, b2);
          }
        } else {
          #pragma unroll
          for (int qq = 0; qq < 4; ++qq)
            #pragma unroll
            for (int e = 0; e < 8; ++e) {
              int j = j0 + qq * 8 + e;
              j = j < 0 ? -j : (j >= LSIG ? 2 * LSIG - 2 - j : j);
              v[qq][e] = bf16r(xb[j]);
            }
        }
      } else {
        #pragma unroll
        for (int qq = 0; qq < 4; ++qq) v[qq] = (short8)(short)0;
      }
      #pragma unroll
      for (int qq = 0; qq < 4; ++qq) *(short8*)&sB[sr][sh + qq * 8] = v[qq];
    }
    __syncthreads();

    const int ra = lane & 15;
    #pragma unroll
    for (int kk = 0; kk < 64; kk += 32) {
      const int col = kk + (lane >> 4) * 8;
      short8 arr[4], aii[4], bfr[4];
      #pragma unroll
      for (int i = 0; i < 4; ++i) {
        const int rm = (wave >> 1) * 64 + i * 16 + ra;
        arr[i] = *(const short8*)&sA[0][rm][col];
        aii[i] = *(const short8*)&sA[1][rm][col];
        const int rn = (wave & 1) * 64 + i * 16 + ra;
        bfr[i] = *(const short8*)&sB[rn][col];
      }
      #pragma unroll
      for (int i = 0; i < 4; ++i)
        #pragma unroll
        for (int j = 0; j < 4; ++j) {
          acc_r[i][j] = __builtin_amdgcn_mfma_f32_16x16x32_bf16(arr[i], bfr[j], acc_r[i][j], 0, 0, 0);
          acc_i[i][j] = __builtin_amdgcn_mfma_f32_16x16x32_bf16(aii[i], bfr[j], acc_i[i][j], 0, 0, 0);
        }
    }
    __syncthreads();
  }

  const int wm0 = m0 + (wave >> 1) * 64;
  const int wn0 = n0 + (wave & 1) * 64;
  const int cl = lane & 15;
  const int rg = (lane >> 4) * 4;
  #pragma unroll
  for (int j = 0; j < 4; ++j) {
    const int f = wn0 + j * 16 + cl;
    if (f >= NFR) continue;
    const int b = f / TFR, t = f - b * TFR;
    float* ob = out + (size_t)b * (CUT * TFR) + t;
    #pragma unroll
    for (int i = 0; i < 4; ++i) {
      #pragma unroll
      for (int r = 0; r < 4; ++r) {
        const int k = wm0 + i * 16 + rg + r;
        if (k < CUT) {
          float re = acc_r[i][j][r], im = acc_i[i][j][r];
          ob[(size_t)k * TFR] = sqrtf(re * re + im * im);
        }
      }
    }
  }
}

extern "C" void kernel_launch(void* const* d_in, const int* in_sizes, int n_in,
                              void* d_out, int out_size, void* d_ws, size_t ws_size,
                              hipStream_t stream) {
  const float* x     = (const float*)d_in[0];
  const float* basis = (const float*)d_in[1];
  float* out = (float*)d_out;

  const size_t sbytes = (size_t)NBATCH * LPAD * sizeof(short);   // 20,611,072
  const size_t hbytes = 2048 * sizeof(float);                    // 8 KB
  const size_t tbytes = 1024 * sizeof(float2);                   // 8 KB each

  if (ws_size >= sbytes + hbytes + 2 * tbytes) {
    short*  XP   = (short*)d_ws;
    float*  hann = (float*)((char*)d_ws + sbytes);
    float2* Tst  = (float2*)((char*)d_ws + sbytes + hbytes);
    float2* Tun  = (float2*)((char*)d_ws + sbytes + hbytes + tbytes);
    pad_signal<<<dim3((LPAD + 2047) / 2048, NBATCH), 256, 0, stream>>>(x, XP);
    make_tables<<<8, 256, 0, stream>>>(hann, Tst, Tun);
    stft_fft<<<NFR / 16, 256, 0, stream>>>(XP, hann, Tst, Tun, out);
  } else {
    stft_gemm_fb<<<dim3(157, 9), 256, 0, stream>>>(basis, x, out);
  }
}

// Round 15
// 103.278 us; speedup vs baseline: 1.2447x; 1.2447x over previous
//
#include <hip/hip_runtime.h>
#include <hip/hip_bf16.h>
#include <cstdint>

// STFT magnitude via real-packed radix-4 FFT (round 15 = r12 + stages0+2 in regs).
// r12 structure (one barrier, 16-frame bf16 mag LDS, global Tun, fully-dirty
// 64B output lines) with ONE surgical change, compositional from two PASSING
// kernels:
//   - load -> fft16(registers, literal twiddles) -> scatter z[16G + (k^gm)]
//     (validated in r14: stages 0+2 == natural-order DFT16 of lane's samples
//     x[lane+64u]; G = base-4 reverse of lane)
//   - fft_stage<4>,<6>,<8> via the r8-proven LDS template (NOT merged -- r14
//     showed the 4+6 merge's 30 persistent VGPRs cost more than it saves)
// Saves 76 of ~250 LDS b64 ops/frame/lane (-30%) at ZERO persistent VGPR cost
// (y/G die after scatter; fft16 twiddles are immediates).
// Lessons: persistent VGPR >128 loses (r10/r11/r14); occupancy first (r5).

#define FILT   2048
#define HOP    512
#define CUT    1025
#define NBATCH 32
#define TFR    626
#define NFR    (NBATCH * TFR)      // 20032
#define LSIG   320000
#define LPAD   (LSIG + FILT)       // 322048
#define N2     1024                // complex FFT length

typedef __attribute__((ext_vector_type(8))) short short8;

__device__ __forceinline__ short bf16r(float f) {
  __hip_bfloat16 h = __float2bfloat16(f);
  return __builtin_bit_cast(short, h);
}
__device__ __forceinline__ float bf2f(uint32_t u) {
  return __builtin_bit_cast(float, u << 16);
}

__device__ __forceinline__ short8 pack8(float4 a, float4 b) {
  short8 v;
  v[0] = bf16r(a.x); v[1] = bf16r(a.y); v[2] = bf16r(a.z); v[3] = bf16r(a.w);
  v[4] = bf16r(b.x); v[5] = bf16r(b.y); v[6] = bf16r(b.z); v[7] = bf16r(b.w);
  return v;
}

// -------- stage 1a: reflect-padded signal, f32 -> bf16 [32][LPAD] --------
__global__ void pad_signal(const float* __restrict__ x, short* __restrict__ XP) {
  const int b = blockIdx.y;
  const int i0 = (blockIdx.x * 256 + threadIdx.x) * 8;
  if (i0 >= LPAD) return;
  const float* xb = x + (size_t)b * LSIG;
  const int j0 = i0 - 1024;
  short8 v;
  if (j0 >= 0 && j0 + 8 <= LSIG) {
    float4 a = *(const float4*)(xb + j0);
    float4 c = *(const float4*)(xb + j0 + 4);
    v = pack8(a, c);
  } else {
    #pragma unroll
    for (int e = 0; e < 8; ++e) {
      int j = j0 + e;
      j = j < 0 ? -j : (j >= LSIG ? 2 * LSIG - 2 - j : j);
      v[e] = bf16r(xb[j]);
    }
  }
  *(short8*)&XP[(size_t)b * LPAD + i0] = v;
}

// -------- stage 1b: twiddle + hann tables --------
__global__ void make_tables(float* __restrict__ hann, float2* __restrict__ Tst,
                            float2* __restrict__ Tun) {
  const int i = blockIdx.x * 256 + threadIdx.x;    // 0..2047
  const float PI2 = 6.283185307179586f;
  if (i < 2048) hann[i] = 0.5f - 0.5f * cosf(PI2 * (float)i / 2048.0f);
  if (i < 1024) {
    float s, c;
    sincosf(-PI2 * (float)i / 1024.0f, &s, &c);
    Tst[i] = make_float2(c, s);                    // W_1024^i (forward)
    sincosf(-PI2 * (float)i / 2048.0f, &s, &c);
    Tun[i] = make_float2(c, s);                    // W_2048^i (unpack)
  }
}

__device__ __forceinline__ float2 cmul(float2 a, float2 b) {
  return make_float2(a.x * b.x - a.y * b.y, a.x * b.y + a.y * b.x);
}
__device__ __forceinline__ float2 cmulc(float2 a, float cx, float cy) {
  return make_float2(a.x * cx - a.y * cy, a.x * cy + a.y * cx);
}

__device__ __forceinline__ int SW(int i) { return i ^ ((i >> 4) & 15); }

// natural-order 16-pt DFT in registers (r10/r14-verified); literal twiddles
__device__ __forceinline__ void fft16(float2* y) {
  static constexpr float TX[4][4] = {
    {1.f, 1.f, 1.f, 1.f},
    {1.f,  0.92387953251128674f,  0.70710678118654752f,  0.38268343236508978f},
    {1.f,  0.70710678118654752f,  0.f,                  -0.70710678118654752f},
    {1.f,  0.38268343236508978f, -0.70710678118654752f, -0.92387953251128674f}};
  static constexpr float TY[4][4] = {
    {0.f, 0.f, 0.f, 0.f},
    {0.f, -0.38268343236508978f, -0.70710678118654752f, -0.92387953251128674f},
    {0.f, -0.70710678118654752f, -1.f,                  -0.70710678118654752f},
    {0.f, -0.92387953251128674f, -0.70710678118654752f,  0.38268343236508978f}};
  float2 G[16];
  #pragma unroll
  for (int n0 = 0; n0 < 4; ++n0) {
    float2 a0 = y[n0], a1 = y[n0 + 4], a2 = y[n0 + 8], a3 = y[n0 + 12];
    float2 e = make_float2(a0.x + a2.x, a0.y + a2.y);
    float2 f = make_float2(a0.x - a2.x, a0.y - a2.y);
    float2 g = make_float2(a1.x + a3.x, a1.y + a3.y);
    float2 h = make_float2(a1.x - a3.x, a1.y - a3.y);
    float2 F0 = make_float2(e.x + g.x, e.y + g.y);
    float2 F1 = make_float2(f.x + h.y, f.y - h.x);   // f - i*h
    float2 F2 = make_float2(e.x - g.x, e.y - g.y);
    float2 F3 = make_float2(f.x - h.y, f.y + h.x);   // f + i*h
    G[n0 * 4 + 0] = F0;
    G[n0 * 4 + 1] = cmulc(F1, TX[n0][1], TY[n0][1]);
    G[n0 * 4 + 2] = cmulc(F2, TX[n0][2], TY[n0][2]);
    G[n0 * 4 + 3] = cmulc(F3, TX[n0][3], TY[n0][3]);
  }
  #pragma unroll
  for (int q = 0; q < 4; ++q) {
    float2 a0 = G[q], a1 = G[4 + q], a2 = G[8 + q], a3 = G[12 + q];
    float2 e = make_float2(a0.x + a2.x, a0.y + a2.y);
    float2 f = make_float2(a0.x - a2.x, a0.y - a2.y);
    float2 g = make_float2(a1.x + a3.x, a1.y + a3.y);
    float2 h = make_float2(a1.x - a3.x, a1.y - a3.y);
    y[q]      = make_float2(e.x + g.x, e.y + g.y);
    y[q + 4]  = make_float2(f.x + h.y, f.y - h.x);
    y[q + 8]  = make_float2(e.x - g.x, e.y - g.y);
    y[q + 12] = make_float2(f.x - h.y, f.y + h.x);
  }
}

// radix-4 DIT stage via LDS (r8-proven), used for LOG=4,6,8
template<int LOG>
__device__ __forceinline__ void fft_stage(float2* z, const float2* tw, int lane) {
  constexpr int M4 = 1 << LOG;
  constexpr int STRIDE = 1 << (8 - LOG);
  #pragma unroll
  for (int u = 0; u < 4; ++u) {
    const int bf = u * 64 + lane;
    const int j  = bf & (M4 - 1);
    const int i0 = ((bf >> LOG) << (LOG + 2)) | j;
    const int i1 = i0 + M4, i2 = i0 + 2 * M4, i3 = i0 + 3 * M4;
    const int p0 = SW(i0), p1 = SW(i1), p2 = SW(i2), p3 = SW(i3);
    float2 a = z[p0], b = z[p1], c = z[p2], d = z[p3];
    if (LOG > 0) {
      b = cmul(b, tw[j * STRIDE]);
      c = cmul(c, tw[2 * j * STRIDE]);
      d = cmul(d, tw[3 * j * STRIDE]);
    }
    const float2 t0 = make_float2(a.x + c.x, a.y + c.y);
    const float2 t1 = make_float2(a.x - c.x, a.y - c.y);
    const float2 t2 = make_float2(b.x + d.x, b.y + d.y);
    const float2 t3 = make_float2(b.x - d.x, b.y - d.y);
    z[p0] = make_float2(t0.x + t2.x, t0.y + t2.y);
    z[p1] = make_float2(t1.x + t3.y, t1.y - t3.x);   // t1 - i*t3
    z[p2] = make_float2(t0.x - t2.x, t0.y - t2.y);
    z[p3] = make_float2(t1.x - t3.y, t1.y + t3.x);   // t1 + i*t3
  }
}

// -------- stage 2: windowed rFFT magnitude, 1 wave = 1 frame --------
__global__ __launch_bounds__(256)
void stft_fft(const short* __restrict__ XP, const float* __restrict__ hann,
              const float2* __restrict__ Tst, const float2* __restrict__ Tun,
              float* __restrict__ out)
{
  __shared__ float2 zsh[4][1024];    // per-wave z, XOR-swizzled   32768 B
  __shared__ float2 tst[1024];       // stage twiddles              8192 B
  __shared__ ushort mag[16][1032];   // bf16 mags, 16 frames       33024 B  (73984 total)

  const int tid = threadIdx.x, wv = tid >> 6, lane = tid & 63;
  #pragma unroll
  for (int u = 0; u < 4; ++u) tst[u * 256 + tid] = Tst[u * 256 + tid];
  __syncthreads();                   // tables ready

  float2* z = zsh[wv];
  const int bid = blockIdx.x;

  // per-lane geometry for the stages-0+2 scatter (r14-validated)
  const int G  = ((lane & 3) << 4) | (lane & 12) | (lane >> 4);  // base-4 reverse
  const int zb = 16 * G, gm = G & 15;

  for (int q = 0; q < 4; ++q) {
    const int f = bid * 16 + q * 4 + wv;
    const int b = f / TFR, t = f - b * TFR;
    const short* base = XP + (size_t)b * LPAD + (size_t)t * HOP;

    // load pairs (coalesced), window, stages 0+2 in registers (= DFT16 of
    // the lane's decimated samples), scatter to block {16G + k} (SW-folded)
    float2 y[16];
    #pragma unroll
    for (int u = 0; u < 16; ++u) {
      const int n = u * 64 + lane;
      const uint32_t pr = *(const uint32_t*)(base + 2 * n);
      const float2 h = *(const float2*)(hann + 2 * n);
      y[u] = make_float2(bf2f(pr & 0xffffu) * h.x, bf2f(pr >> 16) * h.y);
    }
    fft16(y);
    #pragma unroll
    for (int k = 0; k < 16; ++k) z[zb + (k ^ gm)] = y[k];

    fft_stage<4>(z, tst, lane);
    fft_stage<6>(z, tst, lane);
    fft_stage<8>(z, tst, lane);

    // mirror-pair unpack: bins k and 1024-k from one (Zk,Zm,w) triple
    ushort* mrow = mag[q * 4 + wv];
    #pragma unroll
    for (int v = 0; v < 8; ++v) {
      const int k = v * 64 + lane;                     // 0..511
      const float2 Zk = z[SW(k)];
      const int km = (N2 - k) & (N2 - 1);
      const float2 Zm = z[SW(km)];
      const float xer = 0.5f * (Zk.x + Zm.x);
      const float xei = 0.5f * (Zk.y - Zm.y);
      const float xor_ = 0.5f * (Zk.y + Zm.y);
      const float xoi = -0.5f * (Zk.x - Zm.x);
      const float2 w = Tun[k];                         // global, coalesced, L1-hot
      const float px = w.x * xor_ - w.y * xoi;
      const float py = w.x * xoi + w.y * xor_;
      const float Xr = xer + px, Xi = xei + py;
      const float Yr = xer - px, Yi = xei - py;
      mrow[k]        = (ushort)bf16r(sqrtf(Xr * Xr + Xi * Xi));
      mrow[1024 - k] = (ushort)bf16r(sqrtf(Yr * Yr + Yi * Yi));
    }
    if (lane == 0) {
      const float2 Zc = z[SW(512)];
      mrow[512] = (ushort)bf16r(sqrtf(Zc.x * Zc.x + Zc.y * Zc.y));
    }
  }
  __syncthreads();                   // the ONLY post-prologue barrier

  // single write phase: 16 consecutive frames per bin -> fully-dirty 64B lines
  const int fq0 = bid * 16;
  const int b0 = fq0 / TFR, t0 = fq0 - b0 * TFR;
  if (t0 + 15 < TFR) {
    for (int kk = tid; kk < 1025; kk += 256) {
      float* p = out + (size_t)b0 * (CUT * TFR) + (size_t)kk * TFR + t0;
      #pragma unroll
      for (int w2 = 0; w2 < 8; ++w2)
        *(float2*)(p + 2 * w2) =
            make_float2(bf2f(mag[2 * w2][kk]), bf2f(mag[2 * w2 + 1][kk]));
    }
  } else {
    for (int kk = tid; kk < 1025; kk += 256) {
      #pragma unroll
      for (int w2 = 0; w2 < 16; ++w2) {
        const int ff = fq0 + w2;
        const int bb = ff / TFR, tt = ff - bb * TFR;
        out[(size_t)bb * (CUT * TFR) + (size_t)kk * TFR + tt] = bf2f(mag[w2][kk]);
      }
    }
  }
}

// -------- fallback: reg-staged 128x128 MFMA GEMM (no ws needed) --------
typedef __attribute__((ext_vector_type(4))) float f32x4;

__global__ __launch_bounds__(256, 2)
void stft_gemm_fb(const float* __restrict__ basis, const float* __restrict__ x,
                  float* __restrict__ out)
{
  __shared__ alignas(16) short sA[2][128][64];
  __shared__ alignas(16) short sB[128][64];

  const int tid  = threadIdx.x;
  const int wave = tid >> 6;
  const int lane = tid & 63;
  const int n0 = blockIdx.x * 128;
  const int m0 = blockIdx.y * 128;

  f32x4 acc_r[4][4], acc_i[4][4];
  #pragma unroll
  for (int i = 0; i < 4; ++i)
    #pragma unroll
    for (int j = 0; j < 4; ++j) { acc_r[i][j] = (f32x4)0.f; acc_i[i][j] = (f32x4)0.f; }

  const int sr = tid >> 1;
  const int sh = (tid & 1) * 32;

  for (int k0 = 0; k0 < FILT; k0 += 64) {
    #pragma unroll
    for (int p = 0; p < 2; ++p) {
      const int k = m0 + sr;
      short8 v[4];
      if (k < CUT) {
        const float* src = basis + (size_t)(p * CUT + k) * FILT + k0 + sh;
        #pragma unroll
        for (int qq = 0; qq < 4; ++qq) {
          float4 a = *(const float4*)(src + qq * 8);
          float4 b = *(const float4*)(src + qq * 8 + 4);
          v[qq] = pack8(a, b);
        }
      } else {
        #pragma unroll
        for (int qq = 0; qq < 4; ++qq) v[qq] = (short8)(short)0;
      }
      #pragma unroll
      for (int qq = 0; qq < 4; ++qq) *(short8*)&sA[p][sr][sh + qq * 8] = v[qq];
    }
    {
      const int f = n0 + sr;
      short8 v[4];
      if (f < NFR) {
        const int b = f / TFR, t = f - b * TFR;
        const float* xb = x + (size_t)b * LSIG;
        const int j0 = t * HOP + k0 + sh - 1024;
        if (j0 >= 0 && j0 + 32 <= LSIG) {
          #pragma unroll
          for (int qq = 0; qq < 4; ++qq) {
            float4 a  = *(const float4*)(xb + j0 + qq * 8);
            float4 b2 = *(const float4*)(xb + j0 + qq * 8 + 4);
            v[qq] = pack8(a, b2);
          }
        } else {
          #pragma unroll
          for (int qq = 0; qq < 4; ++qq)
            #pragma unroll
            for (int e = 0; e < 8; ++e) {
              int j = j0 + qq * 8 + e;
              j = j < 0 ? -j : (j >= LSIG ? 2 * LSIG - 2 - j : j);
              v[qq][e] = bf16r(xb[j]);
            }
        }
      } else {
        #pragma unroll
        for (int qq = 0; qq < 4; ++qq) v[qq] = (short8)(short)0;
      }
      #pragma unroll
      for (int qq = 0; qq < 4; ++qq) *(short8*)&sB[sr][sh + qq * 8] = v[qq];
    }
    __syncthreads();

    const int ra = lane & 15;
    #pragma unroll
    for (int kk = 0; kk < 64; kk += 32) {
      const int col = kk + (lane >> 4) * 8;
      short8 arr[4], aii[4], bfr[4];
      #pragma unroll
      for (int i = 0; i < 4; ++i) {
        const int rm = (wave >> 1) * 64 + i * 16 + ra;
        arr[i] = *(const short8*)&sA[0][rm][col];
        aii[i] = *(const short8*)&sA[1][rm][col];
        const int rn = (wave & 1) * 64 + i * 16 + ra;
        bfr[i] = *(const short8*)&sB[rn][col];
      }
      #pragma unroll
      for (int i = 0; i < 4; ++i)
        #pragma unroll
        for (int j = 0; j < 4; ++j) {
          acc_r[i][j] = __builtin_amdgcn_mfma_f32_16x16x32_bf16(arr[i], bfr[j], acc_r[i][j], 0, 0, 0);
          acc_i[i][j] = __builtin_amdgcn_mfma_f32_16x16x32_bf16(aii[i], bfr[j], acc_i[i][j], 0, 0, 0);
        }
    }
    __syncthreads();
  }

  const int wm0 = m0 + (wave >> 1) * 64;
  const int wn0 = n0 + (wave & 1) * 64;
  const int cl = lane & 15;
  const int rg = (lane >> 4) * 4;
  #pragma unroll
  for (int j = 0; j < 4; ++j) {
    const int f = wn0 + j * 16 + cl;
    if (f >= NFR) continue;
    const int b = f / TFR, t = f - b * TFR;
    float* ob = out + (size_t)b * (CUT * TFR) + t;
    #pragma unroll
    for (int i = 0; i < 4; ++i) {
      #pragma unroll
      for (int r = 0; r < 4; ++r) {
        const int k = wm0 + i * 16 + rg + r;
        if (k < CUT) {
          float re = acc_r[i][j][r], im = acc_i[i][j][r];
          ob[(size_t)k * TFR] = sqrtf(re * re + im * im);
        }
      }
    }
  }
}

extern "C" void kernel_launch(void* const* d_in, const int* in_sizes, int n_in,
                              void* d_out, int out_size, void* d_ws, size_t ws_size,
                              hipStream_t stream) {
  const float* x     = (const float*)d_in[0];
  const float* basis = (const float*)d_in[1];
  float* out = (float*)d_out;

  const size_t sbytes = (size_t)NBATCH * LPAD * sizeof(short);   // 20,611,072
  const size_t hbytes = 2048 * sizeof(float);                    // 8 KB
  const size_t tbytes = 1024 * sizeof(float2);                   // 8 KB each

  if (ws_size >= sbytes + hbytes + 2 * tbytes) {
    short*  XP   = (short*)d_ws;
    float*  hann = (float*)((char*)d_ws + sbytes);
    float2* Tst  = (float2*)((char*)d_ws + sbytes + hbytes);
    float2* Tun  = (float2*)((char*)d_ws + sbytes + hbytes + tbytes);
    pad_signal<<<dim3((LPAD + 2047) / 2048, NBATCH), 256, 0, stream>>>(x, XP);
    make_tables<<<8, 256, 0, stream>>>(hann, Tst, Tun);
    stft_fft<<<NFR / 16, 256, 0, stream>>>(XP, hann, Tst, Tun, out);
  } else {
    stft_gemm_fb<<<dim3(157, 9), 256, 0, stream>>>(basis, x, out);
  }
}

// Round 16
// 96.389 us; speedup vs baseline: 1.3337x; 1.0715x over previous
//
#include <hip/hip_runtime.h>
#include <hip/hip_bf16.h>
#include <cstdint>

// STFT magnitude via real-packed radix-4 FFT (round 16 = r15 core + r9 split).
// r15 proved the lean FFT core (stages 0+2 in registers, zero persistent VGPR);
// r9 proved coalesced bf16 [f][k] output + LDS-tiled transpose. Combined:
//   - fft kernel: LDS = zsh 32K + tst 8K = 40,960 B -> 4 blocks/CU (2x waves),
//     ZERO post-prologue barriers (no mag staging), 4 frames/block (grid 5008,
//     negligible dispatch tail). Mirror-pair unpack stores mw[k] (lane-
//     contiguous) and mw[1024-k] (contiguous reversed) -- both coalesced.
//   - transpose_out (r9-proven, byte-identical): [f][k] bf16 -> out[b][k][t] f32.
// Lessons kept: persistent VGPR must stay <=128 (r10/r11/r14); occupancy is
// the binding constraint for this latency-bound kernel (r15 post-mortem).

#define FILT   2048
#define HOP    512
#define CUT    1025
#define NBATCH 32
#define TFR    626
#define NFR    (NBATCH * TFR)      // 20032
#define LSIG   320000
#define LPAD   (LSIG + FILT)       // 322048
#define N2     1024                // complex FFT length
#define MWS    1088                // mag_ws row stride (bf16), 128B-aligned
#define KT     17                  // k-tiles (ceil 1025/64)
#define TT     20                  // t-tiles (ceil 626/32)

typedef __attribute__((ext_vector_type(8))) short short8;

__device__ __forceinline__ short bf16r(float f) {
  __hip_bfloat16 h = __float2bfloat16(f);
  return __builtin_bit_cast(short, h);
}
__device__ __forceinline__ float bf2f(uint32_t u) {
  return __builtin_bit_cast(float, u << 16);
}

__device__ __forceinline__ short8 pack8(float4 a, float4 b) {
  short8 v;
  v[0] = bf16r(a.x); v[1] = bf16r(a.y); v[2] = bf16r(a.z); v[3] = bf16r(a.w);
  v[4] = bf16r(b.x); v[5] = bf16r(b.y); v[6] = bf16r(b.z); v[7] = bf16r(b.w);
  return v;
}

// -------- stage 1a: reflect-padded signal, f32 -> bf16 [32][LPAD] --------
__global__ void pad_signal(const float* __restrict__ x, short* __restrict__ XP) {
  const int b = blockIdx.y;
  const int i0 = (blockIdx.x * 256 + threadIdx.x) * 8;
  if (i0 >= LPAD) return;
  const float* xb = x + (size_t)b * LSIG;
  const int j0 = i0 - 1024;
  short8 v;
  if (j0 >= 0 && j0 + 8 <= LSIG) {
    float4 a = *(const float4*)(xb + j0);
    float4 c = *(const float4*)(xb + j0 + 4);
    v = pack8(a, c);
  } else {
    #pragma unroll
    for (int e = 0; e < 8; ++e) {
      int j = j0 + e;
      j = j < 0 ? -j : (j >= LSIG ? 2 * LSIG - 2 - j : j);
      v[e] = bf16r(xb[j]);
    }
  }
  *(short8*)&XP[(size_t)b * LPAD + i0] = v;
}

// -------- stage 1b: twiddle + hann tables --------
__global__ void make_tables(float* __restrict__ hann, float2* __restrict__ Tst,
                            float2* __restrict__ Tun) {
  const int i = blockIdx.x * 256 + threadIdx.x;    // 0..2047
  const float PI2 = 6.283185307179586f;
  if (i < 2048) hann[i] = 0.5f - 0.5f * cosf(PI2 * (float)i / 2048.0f);
  if (i < 1024) {
    float s, c;
    sincosf(-PI2 * (float)i / 1024.0f, &s, &c);
    Tst[i] = make_float2(c, s);                    // W_1024^i (forward)
    sincosf(-PI2 * (float)i / 2048.0f, &s, &c);
    Tun[i] = make_float2(c, s);                    // W_2048^i (unpack)
  }
}

__device__ __forceinline__ float2 cmul(float2 a, float2 b) {
  return make_float2(a.x * b.x - a.y * b.y, a.x * b.y + a.y * b.x);
}
__device__ __forceinline__ float2 cmulc(float2 a, float cx, float cy) {
  return make_float2(a.x * cx - a.y * cy, a.x * cy + a.y * cx);
}

__device__ __forceinline__ int SW(int i) { return i ^ ((i >> 4) & 15); }

// natural-order 16-pt DFT in registers (r10/r14/r15-verified); literal twiddles
__device__ __forceinline__ void fft16(float2* y) {
  static constexpr float TX[4][4] = {
    {1.f, 1.f, 1.f, 1.f},
    {1.f,  0.92387953251128674f,  0.70710678118654752f,  0.38268343236508978f},
    {1.f,  0.70710678118654752f,  0.f,                  -0.70710678118654752f},
    {1.f,  0.38268343236508978f, -0.70710678118654752f, -0.92387953251128674f}};
  static constexpr float TY[4][4] = {
    {0.f, 0.f, 0.f, 0.f},
    {0.f, -0.38268343236508978f, -0.70710678118654752f, -0.92387953251128674f},
    {0.f, -0.70710678118654752f, -1.f,                  -0.70710678118654752f},
    {0.f, -0.92387953251128674f, -0.70710678118654752f,  0.38268343236508978f}};
  float2 G[16];
  #pragma unroll
  for (int n0 = 0; n0 < 4; ++n0) {
    float2 a0 = y[n0], a1 = y[n0 + 4], a2 = y[n0 + 8], a3 = y[n0 + 12];
    float2 e = make_float2(a0.x + a2.x, a0.y + a2.y);
    float2 f = make_float2(a0.x - a2.x, a0.y - a2.y);
    float2 g = make_float2(a1.x + a3.x, a1.y + a3.y);
    float2 h = make_float2(a1.x - a3.x, a1.y - a3.y);
    float2 F0 = make_float2(e.x + g.x, e.y + g.y);
    float2 F1 = make_float2(f.x + h.y, f.y - h.x);   // f - i*h
    float2 F2 = make_float2(e.x - g.x, e.y - g.y);
    float2 F3 = make_float2(f.x - h.y, f.y + h.x);   // f + i*h
    G[n0 * 4 + 0] = F0;
    G[n0 * 4 + 1] = cmulc(F1, TX[n0][1], TY[n0][1]);
    G[n0 * 4 + 2] = cmulc(F2, TX[n0][2], TY[n0][2]);
    G[n0 * 4 + 3] = cmulc(F3, TX[n0][3], TY[n0][3]);
  }
  #pragma unroll
  for (int q = 0; q < 4; ++q) {
    float2 a0 = G[q], a1 = G[4 + q], a2 = G[8 + q], a3 = G[12 + q];
    float2 e = make_float2(a0.x + a2.x, a0.y + a2.y);
    float2 f = make_float2(a0.x - a2.x, a0.y - a2.y);
    float2 g = make_float2(a1.x + a3.x, a1.y + a3.y);
    float2 h = make_float2(a1.x - a3.x, a1.y - a3.y);
    y[q]      = make_float2(e.x + g.x, e.y + g.y);
    y[q + 4]  = make_float2(f.x + h.y, f.y - h.x);
    y[q + 8]  = make_float2(e.x - g.x, e.y - g.y);
    y[q + 12] = make_float2(f.x - h.y, f.y + h.x);
  }
}

// radix-4 DIT stage via LDS (r8-proven), used for LOG=4,6,8
template<int LOG>
__device__ __forceinline__ void fft_stage(float2* z, const float2* tw, int lane) {
  constexpr int M4 = 1 << LOG;
  constexpr int STRIDE = 1 << (8 - LOG);
  #pragma unroll
  for (int u = 0; u < 4; ++u) {
    const int bf = u * 64 + lane;
    const int j  = bf & (M4 - 1);
    const int i0 = ((bf >> LOG) << (LOG + 2)) | j;
    const int i1 = i0 + M4, i2 = i0 + 2 * M4, i3 = i0 + 3 * M4;
    const int p0 = SW(i0), p1 = SW(i1), p2 = SW(i2), p3 = SW(i3);
    float2 a = z[p0], b = z[p1], c = z[p2], d = z[p3];
    if (LOG > 0) {
      b = cmul(b, tw[j * STRIDE]);
      c = cmul(c, tw[2 * j * STRIDE]);
      d = cmul(d, tw[3 * j * STRIDE]);
    }
    const float2 t0 = make_float2(a.x + c.x, a.y + c.y);
    const float2 t1 = make_float2(a.x - c.x, a.y - c.y);
    const float2 t2 = make_float2(b.x + d.x, b.y + d.y);
    const float2 t3 = make_float2(b.x - d.x, b.y - d.y);
    z[p0] = make_float2(t0.x + t2.x, t0.y + t2.y);
    z[p1] = make_float2(t1.x + t3.y, t1.y - t3.x);   // t1 - i*t3
    z[p2] = make_float2(t0.x - t2.x, t0.y - t2.y);
    z[p3] = make_float2(t1.x - t3.y, t1.y + t3.x);   // t1 + i*t3
  }
}

// -------- stage 2: windowed rFFT magnitude -> bf16 MW[f][k] coalesced --------
__global__ __launch_bounds__(256)
void stft_fft(const short* __restrict__ XP, const float* __restrict__ hann,
              const float2* __restrict__ Tst, const float2* __restrict__ Tun,
              ushort* __restrict__ MW)
{
  __shared__ float2 zsh[4][1024];    // per-wave z, XOR-swizzled   32768 B
  __shared__ float2 tst[1024];       // stage twiddles              8192 B  (40960 total)

  const int tid = threadIdx.x, wv = tid >> 6, lane = tid & 63;
  #pragma unroll
  for (int u = 0; u < 4; ++u) tst[u * 256 + tid] = Tst[u * 256 + tid];
  __syncthreads();                   // tables ready; the ONLY barrier

  float2* z = zsh[wv];

  // per-lane geometry for the stages-0+2 scatter (r14/r15-validated)
  const int G  = ((lane & 3) << 4) | (lane & 12) | (lane >> 4);  // base-4 reverse
  const int zb = 16 * G, gm = G & 15;

  const int f = blockIdx.x * 4 + wv;              // 1 frame per wave, grid NFR/4
  const int b = f / TFR, t = f - b * TFR;
  const short* base = XP + (size_t)b * LPAD + (size_t)t * HOP;

  // load pairs (coalesced), window, stages 0+2 in registers, scatter
  float2 y[16];
  #pragma unroll
  for (int u = 0; u < 16; ++u) {
    const int n = u * 64 + lane;
    const uint32_t pr = *(const uint32_t*)(base + 2 * n);
    const float2 h = *(const float2*)(hann + 2 * n);
    y[u] = make_float2(bf2f(pr & 0xffffu) * h.x, bf2f(pr >> 16) * h.y);
  }
  fft16(y);
  #pragma unroll
  for (int k = 0; k < 16; ++k) z[zb + (k ^ gm)] = y[k];

  fft_stage<4>(z, tst, lane);
  fft_stage<6>(z, tst, lane);
  fft_stage<8>(z, tst, lane);

  // mirror-pair unpack -> bf16 MW[f][*]: mw[k] lane-contiguous, mw[1024-k]
  // contiguous-reversed -- both coalesced 128B segments.
  ushort* mw = MW + (size_t)f * MWS;
  #pragma unroll
  for (int v = 0; v < 8; ++v) {
    const int k = v * 64 + lane;                     // 0..511
    const float2 Zk = z[SW(k)];
    const int km = (N2 - k) & (N2 - 1);
    const float2 Zm = z[SW(km)];
    const float xer = 0.5f * (Zk.x + Zm.x);
    const float xei = 0.5f * (Zk.y - Zm.y);
    const float xor_ = 0.5f * (Zk.y + Zm.y);
    const float xoi = -0.5f * (Zk.x - Zm.x);
    const float2 w = Tun[k];                         // global, coalesced, L1-hot
    const float px = w.x * xor_ - w.y * xoi;
    const float py = w.x * xoi + w.y * xor_;
    const float Xr = xer + px, Xi = xei + py;
    const float Yr = xer - px, Yi = xei - py;
    mw[k]        = (ushort)bf16r(sqrtf(Xr * Xr + Xi * Xi));
    mw[1024 - k] = (ushort)bf16r(sqrtf(Yr * Yr + Yi * Yi));
  }
  if (lane == 0) {                                   // k=512 self-paired
    const float2 Zc = z[SW(512)];
    mw[512] = (ushort)bf16r(sqrtf(Zc.x * Zc.x + Zc.y * Zc.y));
  }
}

// -------- stage 3: transpose [f][k] bf16 -> out[b][k][t] f32 (r9-proven) --------
__global__ __launch_bounds__(256)
void transpose_out(const ushort* __restrict__ MW, float* __restrict__ out) {
  __shared__ float tile[64][33];
  const int b  = blockIdx.y;
  const int kt = blockIdx.x % KT;
  const int tt = blockIdx.x / KT;
  const int k0 = kt * 64, t0 = tt * 32;
  const int tid = threadIdx.x;
  const int r = tid >> 5, c = tid & 31;

  #pragma unroll
  for (int s = 0; s < 4; ++s) {
    const int t = t0 + r + 8 * s;
    if (t < TFR) {
      const uint32_t pr =
        *(const uint32_t*)(MW + (size_t)(b * TFR + t) * MWS + k0 + 2 * c);
      tile[2 * c][r + 8 * s]     = bf2f(pr & 0xffffu);
      tile[2 * c + 1][r + 8 * s] = bf2f(pr >> 16);
    }
  }
  __syncthreads();

  const int kk = tid >> 2, toff = (tid & 3) * 8;
  const int k = k0 + kk;
  if (k < CUT) {
    float* pptr = out + (size_t)b * (CUT * TFR) + (size_t)k * TFR + t0 + toff;
    if (t0 + 32 <= TFR) {
      float4 v0 = make_float4(tile[kk][toff], tile[kk][toff + 1],
                              tile[kk][toff + 2], tile[kk][toff + 3]);
      float4 v1 = make_float4(tile[kk][toff + 4], tile[kk][toff + 5],
                              tile[kk][toff + 6], tile[kk][toff + 7]);
      *(float4*)pptr = v0;
      *(float4*)(pptr + 4) = v1;
    } else {
      #pragma unroll
      for (int e = 0; e < 8; ++e) {
        const int t = t0 + toff + e;
        if (t < TFR) pptr[e] = tile[kk][toff + e];
      }
    }
  }
}

// -------- fallback: reg-staged 128x128 MFMA GEMM (no ws needed) --------
typedef __attribute__((ext_vector_type(4))) float f32x4;

__global__ __launch_bounds__(256, 2)
void stft_gemm_fb(const float* __restrict__ basis, const float* __restrict__ x,
                  float* __restrict__ out)
{
  __shared__ alignas(16) short sA[2][128][64];
  __shared__ alignas(16) short sB[128][64];

  const int tid  = threadIdx.x;
  const int wave = tid >> 6;
  const int lane = tid & 63;
  const int n0 = blockIdx.x * 128;
  const int m0 = blockIdx.y * 128;

  f32x4 acc_r[4][4], acc_i[4][4];
  #pragma unroll
  for (int i = 0; i < 4; ++i)
    #pragma unroll
    for (int j = 0; j < 4; ++j) { acc_r[i][j] = (f32x4)0.f; acc_i[i][j] = (f32x4)0.f; }

  const int sr = tid >> 1;
  const int sh = (tid & 1) * 32;

  for (int k0 = 0; k0 < FILT; k0 += 64) {
    #pragma unroll
    for (int p = 0; p < 2; ++p) {
      const int k = m0 + sr;
      short8 v[4];
      if (k < CUT) {
        const float* src = basis + (size_t)(p * CUT + k) * FILT + k0 + sh;
        #pragma unroll
        for (int qq = 0; qq < 4; ++qq) {
          float4 a = *(const float4*)(src + qq * 8);
          float4 b = *(const float4*)(src + qq * 8 + 4);
          v[qq] = pack8(a, b);
        }
      } else {
        #pragma unroll
        for (int qq = 0; qq < 4; ++qq) v[qq] = (short8)(short)0;
      }
      #pragma unroll
      for (int qq = 0; qq < 4; ++qq) *(short8*)&sA[p][sr][sh + qq * 8] = v[qq];
    }
    {
      const int f = n0 + sr;
      short8 v[4];
      if (f < NFR) {
        const int b = f / TFR, t = f - b * TFR;
        const float* xb = x + (size_t)b * LSIG;
        const int j0 = t * HOP + k0 + sh - 1024;
        if (j0 >= 0 && j0 + 32 <= LSIG) {
          #pragma unroll
          for (int qq = 0; qq < 4; ++qq) {
            float4 a  = *(const float4*)(xb + j0 + qq * 8);
            float4 b2 = *(const float4*)(xb + j0 + qq * 8 + 4);
            v[qq] = pack8(a, b2);
          }
        } else {
          #pragma unroll
          for (int qq = 0; qq < 4; ++qq)
            #pragma unroll
            for (int e = 0; e < 8; ++e) {
              int j = j0 + qq * 8 + e;
              j = j < 0 ? -j : (j >= LSIG ? 2 * LSIG - 2 - j : j);
              v[qq][e] = bf16r(xb[j]);
            }
        }
      } else {
        #pragma unroll
        for (int qq = 0; qq < 4; ++qq) v[qq] = (short8)(short)0;
      }
      #pragma unroll
      for (int qq = 0; qq < 4; ++qq) *(short8*)&sB[sr][sh + qq * 8] = v[qq];
    }
    __syncthreads();

    const int ra = lane & 15;
    #pragma unroll
    for (int kk = 0; kk < 64; kk += 32) {
      const int col = kk + (lane >> 4) * 8;
      short8 arr[4], aii[4], bfr[4];
      #pragma unroll
      for (int i = 0; i < 4; ++i) {
        const int rm = (wave >> 1) * 64 + i * 16 + ra;
        arr[i] = *(const short8*)&sA[0][rm][col];
        aii[i] = *(const short8*)&sA[1][rm][col];
        const int rn = (wave & 1) * 64 + i * 16 + ra;
        bfr[i] = *(const short8*)&sB[rn][col];
      }
      #pragma unroll
      for (int i = 0; i < 4; ++i)
        #pragma unroll
        for (int j = 0; j < 4; ++j) {
          acc_r[i][j] = __builtin_amdgcn_mfma_f32_16x16x32_bf16(arr[i], bfr[j], acc_r[i][j], 0, 0, 0);
          acc_i[i][j] = __builtin_amdgcn_mfma_f32_16x16x32_bf16(aii[i], bfr[j], acc_i[i][j], 0, 0, 0);
        }
    }
    __syncthreads();
  }

  const int wm0 = m0 + (wave >> 1) * 64;
  const int wn0 = n0 + (wave & 1) * 64;
  const int cl = lane & 15;
  const int rg = (lane >> 4) * 4;
  #pragma unroll
  for (int j = 0; j < 4; ++j) {
    const int f = wn0 + j * 16 + cl;
    if (f >= NFR) continue;
    const int b = f / TFR, t = f - b * TFR;
    float* ob = out + (size_t)b * (CUT * TFR) + t;
    #pragma unroll
    for (int i = 0; i < 4; ++i) {
      #pragma unroll
      for (int r = 0; r < 4; ++r) {
        const int k = wm0 + i * 16 + rg + r;
        if (k < CUT) {
          float re = acc_r[i][j][r], im = acc_i[i][j][r];
          ob[(size_t)k * TFR] = sqrtf(re * re + im * im);
        }
      }
    }
  }
}

extern "C" void kernel_launch(void* const* d_in, const int* in_sizes, int n_in,
                              void* d_out, int out_size, void* d_ws, size_t ws_size,
                              hipStream_t stream) {
  const float* x     = (const float*)d_in[0];
  const float* basis = (const float*)d_in[1];
  float* out = (float*)d_out;

  const size_t sbytes = (size_t)NBATCH * LPAD * sizeof(short);   // 20,611,072
  const size_t hbytes = 2048 * sizeof(float);
  const size_t tbytes = 1024 * sizeof(float2);
  const size_t mbytes = (size_t)NFR * MWS * sizeof(ushort);      // 43,589,632

  if (ws_size >= sbytes + hbytes + 2 * tbytes + mbytes) {
    short*  XP   = (short*)d_ws;
    float*  hann = (float*)((char*)d_ws + sbytes);
    float2* Tst  = (float2*)((char*)d_ws + sbytes + hbytes);
    float2* Tun  = (float2*)((char*)d_ws + sbytes + hbytes + tbytes);
    ushort* MW   = (ushort*)((char*)d_ws + sbytes + hbytes + 2 * tbytes);
    pad_signal<<<dim3((LPAD + 2047) / 2048, NBATCH), 256, 0, stream>>>(x, XP);
    make_tables<<<8, 256, 0, stream>>>(hann, Tst, Tun);
    stft_fft<<<NFR / 4, 256, 0, stream>>>(XP, hann, Tst, Tun, MW);
    transpose_out<<<dim3(KT * TT, NBATCH), 256, 0, stream>>>(MW, out);
  } else {
    stft_gemm_fb<<<dim3(157, 9), 256, 0, stream>>>(basis, x, out);
  }
}

// Round 17
// 88.874 us; speedup vs baseline: 1.4465x; 1.0846x over previous
//
#include <hip/hip_runtime.h>
#include <hip/hip_bf16.h>
#include <cstdint>

// STFT magnitude via real-packed radix-4 FFT (round 17 = r16 + two removals).
//   1. pad_signal kernel ELIMINATED: fft kernel reads f32 x directly. t is
//      wave-uniform; interior frames (2 <= t <= 623, exact) take a float2
//      fast path (coalesced, x is L3-resident); only t in {0,1,624,625} runs
//      per-element reflect. Saves ~13us + 82MB ws traffic, improves accuracy.
//   2. stages 4+6 merged in registers (r14's verified math, incl. the
//      stage-4 STRIDE=16 twiddle fix). r14 failed only on VGPR>128 at
//      2 blocks/CU; r16's base is VGPR=60 -> merge lands ~100, still <=128,
//      4 blocks/CU unchanged. Saves 41 of 164 LDS b64 ops/frame/lane and one
//      serial LDS round-trip.
// Structure otherwise r16: 1 frame/wave, grid NFR/4, one prologue barrier,
// coalesced bf16 MW[f][k] out, r9-proven transpose kernel.

#define FILT   2048
#define HOP    512
#define CUT    1025
#define NBATCH 32
#define TFR    626
#define NFR    (NBATCH * TFR)      // 20032
#define LSIG   320000
#define N2     1024                // complex FFT length
#define MWS    1088                // mag_ws row stride (bf16), 128B-aligned
#define KT     17                  // k-tiles (ceil 1025/64)
#define TT     20                  // t-tiles (ceil 626/32)

typedef __attribute__((ext_vector_type(8))) short short8;

__device__ __forceinline__ short bf16r(float f) {
  __hip_bfloat16 h = __float2bfloat16(f);
  return __builtin_bit_cast(short, h);
}
__device__ __forceinline__ float bf2f(uint32_t u) {
  return __builtin_bit_cast(float, u << 16);
}

__device__ __forceinline__ short8 pack8(float4 a, float4 b) {
  short8 v;
  v[0] = bf16r(a.x); v[1] = bf16r(a.y); v[2] = bf16r(a.z); v[3] = bf16r(a.w);
  v[4] = bf16r(b.x); v[5] = bf16r(b.y); v[6] = bf16r(b.z); v[7] = bf16r(b.w);
  return v;
}

// -------- stage 1: twiddle + hann tables --------
__global__ void make_tables(float* __restrict__ hann, float2* __restrict__ Tst,
                            float2* __restrict__ Tun) {
  const int i = blockIdx.x * 256 + threadIdx.x;    // 0..2047
  const float PI2 = 6.283185307179586f;
  if (i < 2048) hann[i] = 0.5f - 0.5f * cosf(PI2 * (float)i / 2048.0f);
  if (i < 1024) {
    float s, c;
    sincosf(-PI2 * (float)i / 1024.0f, &s, &c);
    Tst[i] = make_float2(c, s);                    // W_1024^i (forward)
    sincosf(-PI2 * (float)i / 2048.0f, &s, &c);
    Tun[i] = make_float2(c, s);                    // W_2048^i (unpack)
  }
}

__device__ __forceinline__ float2 cmul(float2 a, float2 b) {
  return make_float2(a.x * b.x - a.y * b.y, a.x * b.y + a.y * b.x);
}
__device__ __forceinline__ float2 cmulc(float2 a, float cx, float cy) {
  return make_float2(a.x * cx - a.y * cy, a.x * cy + a.y * cx);
}

__device__ __forceinline__ int SW(int i) { return i ^ ((i >> 4) & 15); }

// natural-order 16-pt DFT in registers (r10/r14/r15-verified); literal twiddles
__device__ __forceinline__ void fft16(float2* y) {
  static constexpr float TX[4][4] = {
    {1.f, 1.f, 1.f, 1.f},
    {1.f,  0.92387953251128674f,  0.70710678118654752f,  0.38268343236508978f},
    {1.f,  0.70710678118654752f,  0.f,                  -0.70710678118654752f},
    {1.f,  0.38268343236508978f, -0.70710678118654752f, -0.92387953251128674f}};
  static constexpr float TY[4][4] = {
    {0.f, 0.f, 0.f, 0.f},
    {0.f, -0.38268343236508978f, -0.70710678118654752f, -0.92387953251128674f},
    {0.f, -0.70710678118654752f, -1.f,                  -0.70710678118654752f},
    {0.f, -0.92387953251128674f, -0.70710678118654752f,  0.38268343236508978f}};
  float2 G[16];
  #pragma unroll
  for (int n0 = 0; n0 < 4; ++n0) {
    float2 a0 = y[n0], a1 = y[n0 + 4], a2 = y[n0 + 8], a3 = y[n0 + 12];
    float2 e = make_float2(a0.x + a2.x, a0.y + a2.y);
    float2 f = make_float2(a0.x - a2.x, a0.y - a2.y);
    float2 g = make_float2(a1.x + a3.x, a1.y + a3.y);
    float2 h = make_float2(a1.x - a3.x, a1.y - a3.y);
    float2 F0 = make_float2(e.x + g.x, e.y + g.y);
    float2 F1 = make_float2(f.x + h.y, f.y - h.x);   // f - i*h
    float2 F2 = make_float2(e.x - g.x, e.y - g.y);
    float2 F3 = make_float2(f.x - h.y, f.y + h.x);   // f + i*h
    G[n0 * 4 + 0] = F0;
    G[n0 * 4 + 1] = cmulc(F1, TX[n0][1], TY[n0][1]);
    G[n0 * 4 + 2] = cmulc(F2, TX[n0][2], TY[n0][2]);
    G[n0 * 4 + 3] = cmulc(F3, TX[n0][3], TY[n0][3]);
  }
  #pragma unroll
  for (int q = 0; q < 4; ++q) {
    float2 a0 = G[q], a1 = G[4 + q], a2 = G[8 + q], a3 = G[12 + q];
    float2 e = make_float2(a0.x + a2.x, a0.y + a2.y);
    float2 f = make_float2(a0.x - a2.x, a0.y - a2.y);
    float2 g = make_float2(a1.x + a3.x, a1.y + a3.y);
    float2 h = make_float2(a1.x - a3.x, a1.y - a3.y);
    y[q]      = make_float2(e.x + g.x, e.y + g.y);
    y[q + 4]  = make_float2(f.x + h.y, f.y - h.x);
    y[q + 8]  = make_float2(e.x - g.x, e.y - g.y);
    y[q + 12] = make_float2(f.x - h.y, f.y + h.x);
  }
}

// radix-4 DIT stage via LDS (r8-proven), used for LOG=8 only
template<int LOG>
__device__ __forceinline__ void fft_stage(float2* z, const float2* tw, int lane) {
  constexpr int M4 = 1 << LOG;
  constexpr int STRIDE = 1 << (8 - LOG);
  #pragma unroll
  for (int u = 0; u < 4; ++u) {
    const int bf = u * 64 + lane;
    const int j  = bf & (M4 - 1);
    const int i0 = ((bf >> LOG) << (LOG + 2)) | j;
    const int i1 = i0 + M4, i2 = i0 + 2 * M4, i3 = i0 + 3 * M4;
    const int p0 = SW(i0), p1 = SW(i1), p2 = SW(i2), p3 = SW(i3);
    float2 a = z[p0], b = z[p1], c = z[p2], d = z[p3];
    if (LOG > 0) {
      b = cmul(b, tw[j * STRIDE]);
      c = cmul(c, tw[2 * j * STRIDE]);
      d = cmul(d, tw[3 * j * STRIDE]);
    }
    const float2 t0 = make_float2(a.x + c.x, a.y + c.y);
    const float2 t1 = make_float2(a.x - c.x, a.y - c.y);
    const float2 t2 = make_float2(b.x + d.x, b.y + d.y);
    const float2 t3 = make_float2(b.x - d.x, b.y - d.y);
    z[p0] = make_float2(t0.x + t2.x, t0.y + t2.y);
    z[p1] = make_float2(t1.x + t3.y, t1.y - t3.x);   // t1 - i*t3
    z[p2] = make_float2(t0.x - t2.x, t0.y - t2.y);
    z[p3] = make_float2(t1.x - t3.y, t1.y + t3.x);   // t1 + i*t3
  }
}

// -------- stage 2: windowed rFFT magnitude -> bf16 MW[f][k] coalesced --------
__global__ __launch_bounds__(256)
void stft_fft(const float* __restrict__ x, const float* __restrict__ hann,
              const float2* __restrict__ Tst, const float2* __restrict__ Tun,
              ushort* __restrict__ MW)
{
  __shared__ float2 zsh[4][1024];    // per-wave z, XOR-swizzled   32768 B
  __shared__ float2 tst[1024];       // stage twiddles              8192 B  (40960 total)

  const int tid = threadIdx.x, wv = tid >> 6, lane = tid & 63;
  #pragma unroll
  for (int u = 0; u < 4; ++u) tst[u * 256 + tid] = Tst[u * 256 + tid];
  __syncthreads();                   // tables ready; the ONLY barrier

  float2* z = zsh[wv];

  // per-lane geometry
  const int G  = ((lane & 3) << 4) | (lane & 12) | (lane >> 4);  // base-4 reverse
  const int zb = 16 * G, gm = G & 15;
  const int j0 = lane & 15, B = lane >> 4;

  const int f = blockIdx.x * 4 + wv;              // 1 frame per wave, grid NFR/4
  const int b = f / TFR, t = f - b * TFR;
  const float* xb = x + (size_t)b * LSIG;
  const int off = t * HOP - 1024;

  // load f32 pairs directly, window, stages 0+2 in registers, scatter
  float2 y[16];
  if (t >= 2 && t <= 623) {                       // interior: off>=0, off+2047<LSIG
    #pragma unroll
    for (int u = 0; u < 16; ++u) {
      const int n = u * 64 + lane;
      const float2 p = *(const float2*)(xb + off + 2 * n);
      const float2 h = *(const float2*)(hann + 2 * n);
      y[u] = make_float2(p.x * h.x, p.y * h.y);
    }
  } else {                                        // boundary: per-element reflect
    #pragma unroll
    for (int u = 0; u < 16; ++u) {
      const int n = u * 64 + lane;
      int ja = off + 2 * n, jb = ja + 1;
      ja = ja < 0 ? -ja : (ja >= LSIG ? 2 * LSIG - 2 - ja : ja);
      jb = jb < 0 ? -jb : (jb >= LSIG ? 2 * LSIG - 2 - jb : jb);
      const float2 h = *(const float2*)(hann + 2 * n);
      y[u] = make_float2(xb[ja] * h.x, xb[jb] * h.y);
    }
  }
  fft16(y);
  #pragma unroll
  for (int k = 0; k < 16; ++k) z[zb + (k ^ gm)] = y[k];

  // stages 4+6 in registers on closed set {j0 + 16a + 64b2 + 256B} (r14 math)
  {
    float2 g[4][4];
    #pragma unroll
    for (int a = 0; a < 4; ++a)
      #pragma unroll
      for (int b2 = 0; b2 < 4; ++b2)
        g[a][b2] = z[16 * (a + 4 * b2 + 16 * B) + (j0 ^ (a + 4 * b2))];
    // stage 4 (over a): STRIDE=16 -> twiddles tst[16*j0 * {1,2,3}]
    const float2 w41 = tst[16 * j0], w42 = tst[32 * j0], w43 = tst[48 * j0];
    #pragma unroll
    for (int b2 = 0; b2 < 4; ++b2) {
      float2 a0 = g[0][b2];
      float2 a1 = cmul(g[1][b2], w41);
      float2 a2 = cmul(g[2][b2], w42);
      float2 a3 = cmul(g[3][b2], w43);
      const float2 t0 = make_float2(a0.x + a2.x, a0.y + a2.y);
      const float2 t1 = make_float2(a0.x - a2.x, a0.y - a2.y);
      const float2 t2 = make_float2(a1.x + a3.x, a1.y + a3.y);
      const float2 t3 = make_float2(a1.x - a3.x, a1.y - a3.y);
      g[0][b2] = make_float2(t0.x + t2.x, t0.y + t2.y);
      g[1][b2] = make_float2(t1.x + t3.y, t1.y - t3.x);
      g[2][b2] = make_float2(t0.x - t2.x, t0.y - t2.y);
      g[3][b2] = make_float2(t1.x - t3.y, t1.y + t3.x);
    }
    // stage 6 (over b2): STRIDE=4 -> twiddles tst[4*(j0+16*mp) * {1,2,3}]
    #pragma unroll
    for (int mp = 0; mp < 4; ++mp) {
      const int jj = 4 * (j0 + 16 * mp);
      float2 a0 = g[mp][0];
      float2 a1 = cmul(g[mp][1], tst[jj]);
      float2 a2 = cmul(g[mp][2], tst[2 * jj]);
      float2 a3 = cmul(g[mp][3], tst[3 * jj]);
      const float2 t0 = make_float2(a0.x + a2.x, a0.y + a2.y);
      const float2 t1 = make_float2(a0.x - a2.x, a0.y - a2.y);
      const float2 t2 = make_float2(a1.x + a3.x, a1.y + a3.y);
      const float2 t3 = make_float2(a1.x - a3.x, a1.y - a3.y);
      g[mp][0] = make_float2(t0.x + t2.x, t0.y + t2.y);
      g[mp][1] = make_float2(t1.x + t3.y, t1.y - t3.x);
      g[mp][2] = make_float2(t0.x - t2.x, t0.y - t2.y);
      g[mp][3] = make_float2(t1.x - t3.y, t1.y + t3.x);
    }
    #pragma unroll
    for (int mp = 0; mp < 4; ++mp)
      #pragma unroll
      for (int m2 = 0; m2 < 4; ++m2)
        z[16 * (mp + 4 * m2 + 16 * B) + (j0 ^ (mp + 4 * m2))] = g[mp][m2];
  }

  fft_stage<8>(z, tst, lane);

  // mirror-pair unpack -> bf16 MW[f][*] (both directions coalesced)
  ushort* mw = MW + (size_t)f * MWS;
  #pragma unroll
  for (int v = 0; v < 8; ++v) {
    const int k = v * 64 + lane;                     // 0..511
    const float2 Zk = z[SW(k)];
    const int km = (N2 - k) & (N2 - 1);
    const float2 Zm = z[SW(km)];
    const float xer = 0.5f * (Zk.x + Zm.x);
    const float xei = 0.5f * (Zk.y - Zm.y);
    const float xor_ = 0.5f * (Zk.y + Zm.y);
    const float xoi = -0.5f * (Zk.x - Zm.x);
    const float2 w = Tun[k];                         // global, coalesced, L1-hot
    const float px = w.x * xor_ - w.y * xoi;
    const float py = w.x * xoi + w.y * xor_;
    const float Xr = xer + px, Xi = xei + py;
    const float Yr = xer - px, Yi = xei - py;
    mw[k]        = (ushort)bf16r(sqrtf(Xr * Xr + Xi * Xi));
    mw[1024 - k] = (ushort)bf16r(sqrtf(Yr * Yr + Yi * Yi));
  }
  if (lane == 0) {                                   // k=512 self-paired
    const float2 Zc = z[SW(512)];
    mw[512] = (ushort)bf16r(sqrtf(Zc.x * Zc.x + Zc.y * Zc.y));
  }
}

// -------- stage 3: transpose [f][k] bf16 -> out[b][k][t] f32 (r9-proven) --------
__global__ __launch_bounds__(256)
void transpose_out(const ushort* __restrict__ MW, float* __restrict__ out) {
  __shared__ float tile[64][33];
  const int b  = blockIdx.y;
  const int kt = blockIdx.x % KT;
  const int tt = blockIdx.x / KT;
  const int k0 = kt * 64, t0 = tt * 32;
  const int tid = threadIdx.x;
  const int r = tid >> 5, c = tid & 31;

  #pragma unroll
  for (int s = 0; s < 4; ++s) {
    const int t = t0 + r + 8 * s;
    if (t < TFR) {
      const uint32_t pr =
        *(const uint32_t*)(MW + (size_t)(b * TFR + t) * MWS + k0 + 2 * c);
      tile[2 * c][r + 8 * s]     = bf2f(pr & 0xffffu);
      tile[2 * c + 1][r + 8 * s] = bf2f(pr >> 16);
    }
  }
  __syncthreads();

  const int kk = tid >> 2, toff = (tid & 3) * 8;
  const int k = k0 + kk;
  if (k < CUT) {
    float* pptr = out + (size_t)b * (CUT * TFR) + (size_t)k * TFR + t0 + toff;
    if (t0 + 32 <= TFR) {
      float4 v0 = make_float4(tile[kk][toff], tile[kk][toff + 1],
                              tile[kk][toff + 2], tile[kk][toff + 3]);
      float4 v1 = make_float4(tile[kk][toff + 4], tile[kk][toff + 5],
                              tile[kk][toff + 6], tile[kk][toff + 7]);
      *(float4*)pptr = v0;
      *(float4*)(pptr + 4) = v1;
    } else {
      #pragma unroll
      for (int e = 0; e < 8; ++e) {
        const int t = t0 + toff + e;
        if (t < TFR) pptr[e] = tile[kk][toff + e];
      }
    }
  }
}

// -------- fallback: reg-staged 128x128 MFMA GEMM (no ws needed) --------
typedef __attribute__((ext_vector_type(4))) float f32x4;

__global__ __launch_bounds__(256, 2)
void stft_gemm_fb(const float* __restrict__ basis, const float* __restrict__ x,
                  float* __restrict__ out)
{
  __shared__ alignas(16) short sA[2][128][64];
  __shared__ alignas(16) short sB[128][64];

  const int tid  = threadIdx.x;
  const int wave = tid >> 6;
  const int lane = tid & 63;
  const int n0 = blockIdx.x * 128;
  const int m0 = blockIdx.y * 128;

  f32x4 acc_r[4][4], acc_i[4][4];
  #pragma unroll
  for (int i = 0; i < 4; ++i)
    #pragma unroll
    for (int j = 0; j < 4; ++j) { acc_r[i][j] = (f32x4)0.f; acc_i[i][j] = (f32x4)0.f; }

  const int sr = tid >> 1;
  const int sh = (tid & 1) * 32;

  for (int k0 = 0; k0 < FILT; k0 += 64) {
    #pragma unroll
    for (int p = 0; p < 2; ++p) {
      const int k = m0 + sr;
      short8 v[4];
      if (k < CUT) {
        const float* src = basis + (size_t)(p * CUT + k) * FILT + k0 + sh;
        #pragma unroll
        for (int qq = 0; qq < 4; ++qq) {
          float4 a = *(const float4*)(src + qq * 8);
          float4 b = *(const float4*)(src + qq * 8 + 4);
          v[qq] = pack8(a, b);
        }
      } else {
        #pragma unroll
        for (int qq = 0; qq < 4; ++qq) v[qq] = (short8)(short)0;
      }
      #pragma unroll
      for (int qq = 0; qq < 4; ++qq) *(short8*)&sA[p][sr][sh + qq * 8] = v[qq];
    }
    {
      const int f = n0 + sr;
      short8 v[4];
      if (f < NFR) {
        const int b = f / TFR, t = f - b * TFR;
        const float* xb = x + (size_t)b * LSIG;
        const int j0 = t * HOP + k0 + sh - 1024;
        if (j0 >= 0 && j0 + 32 <= LSIG) {
          #pragma unroll
          for (int qq = 0; qq < 4; ++qq) {
            float4 a  = *(const float4*)(xb + j0 + qq * 8);
            float4 b2 = *(const float4*)(xb + j0 + qq * 8 + 4);
            v[qq] = pack8(a, b2);
          }
        } else {
          #pragma unroll
          for (int qq = 0; qq < 4; ++qq)
            #pragma unroll
            for (int e = 0; e < 8; ++e) {
              int j = j0 + qq * 8 + e;
              j = j < 0 ? -j : (j >= LSIG ? 2 * LSIG - 2 - j : j);
              v[qq][e] = bf16r(xb[j]);
            }
        }
      } else {
        #pragma unroll
        for (int qq = 0; qq < 4; ++qq) v[qq] = (short8)(short)0;
      }
      #pragma unroll
      for (int qq = 0; qq < 4; ++qq) *(short8*)&sB[sr][sh + qq * 8] = v[qq];
    }
    __syncthreads();

    const int ra = lane & 15;
    #pragma unroll
    for (int kk = 0; kk < 64; kk += 32) {
      const int col = kk + (lane >> 4) * 8;
      short8 arr[4], aii[4], bfr[4];
      #pragma unroll
      for (int i = 0; i < 4; ++i) {
        const int rm = (wave >> 1) * 64 + i * 16 + ra;
        arr[i] = *(const short8*)&sA[0][rm][col];
        aii[i] = *(const short8*)&sA[1][rm][col];
        const int rn = (wave & 1) * 64 + i * 16 + ra;
        bfr[i] = *(const short8*)&sB[rn][col];
      }
      #pragma unroll
      for (int i = 0; i < 4; ++i)
        #pragma unroll
        for (int j = 0; j < 4; ++j) {
          acc_r[i][j] = __builtin_amdgcn_mfma_f32_16x16x32_bf16(arr[i], bfr[j], acc_r[i][j], 0, 0, 0);
          acc_i[i][j] = __builtin_amdgcn_mfma_f32_16x16x32_bf16(aii[i], bfr[j], acc_i[i][j], 0, 0, 0);
        }
    }
    __syncthreads();
  }

  const int wm0 = m0 + (wave >> 1) * 64;
  const int wn0 = n0 + (wave & 1) * 64;
  const int cl = lane & 15;
  const int rg = (lane >> 4) * 4;
  #pragma unroll
  for (int j = 0; j < 4; ++j) {
    const int f = wn0 + j * 16 + cl;
    if (f >= NFR) continue;
    const int b = f / TFR, t = f - b * TFR;
    float* ob = out + (size_t)b * (CUT * TFR) + t;
    #pragma unroll
    for (int i = 0; i < 4; ++i) {
      #pragma unroll
      for (int r = 0; r < 4; ++r) {
        const int k = wm0 + i * 16 + rg + r;
        if (k < CUT) {
          float re = acc_r[i][j][r], im = acc_i[i][j][r];
          ob[(size_t)k * TFR] = sqrtf(re * re + im * im);
        }
      }
    }
  }
}

extern "C" void kernel_launch(void* const* d_in, const int* in_sizes, int n_in,
                              void* d_out, int out_size, void* d_ws, size_t ws_size,
                              hipStream_t stream) {
  const float* x     = (const float*)d_in[0];
  const float* basis = (const float*)d_in[1];
  float* out = (float*)d_out;

  const size_t hbytes = 2048 * sizeof(float);                    // 8 KB
  const size_t tbytes = 1024 * sizeof(float2);                   // 8 KB each
  const size_t mbytes = (size_t)NFR * MWS * sizeof(ushort);      // 43,589,632

  if (ws_size >= hbytes + 2 * tbytes + mbytes) {
    float*  hann = (float*)d_ws;
    float2* Tst  = (float2*)((char*)d_ws + hbytes);
    float2* Tun  = (float2*)((char*)d_ws + hbytes + tbytes);
    ushort* MW   = (ushort*)((char*)d_ws + hbytes + 2 * tbytes);
    make_tables<<<8, 256, 0, stream>>>(hann, Tst, Tun);
    stft_fft<<<NFR / 4, 256, 0, stream>>>(x, hann, Tst, Tun, MW);
    transpose_out<<<dim3(KT * TT, NBATCH), 256, 0, stream>>>(MW, out);
  } else {
    stft_gemm_fb<<<dim3(157, 9), 256, 0, stream>>>(basis, x, out);
  }
}